// Round 1
// baseline (414.076 us; speedup 1.0000x reference)
//
#include <hip/hip_runtime.h>
#include <stdint.h>
#include <stddef.h>

#define KH   512
#define NC   6
#define DF   3072          // KH * NC
#define EPSF 1e-5f

typedef __attribute__((ext_vector_type(4))) float f32x4;
typedef __attribute__((ext_vector_type(8))) short bf16x8;

__device__ __forceinline__ unsigned short f2bf(float f) {
  union { float f; unsigned u; } c; c.f = f;
  unsigned u = c.u;
  u += 0x7fffu + ((u >> 16) & 1u);     // round-to-nearest-even
  return (unsigned short)(u >> 16);
}

// Pack B' = [alpha | beta]^T as bf16, row-major in k' (row = o, 1024 k' per row).
// wbt[o*1024 + k]       = W[o,k,0] - W[o,k,1]   (alpha)
// wbt[o*1024 + 512 + k] = W[o,k,1]              (beta)
__global__ __launch_bounds__(256) void prep_w(const float* __restrict__ cw,
                                              unsigned short* __restrict__ wbt) {
  int o = blockIdx.x;
  for (int k = threadIdx.x; k < KH; k += 256) {
    float w0 = cw[o * 1024 + k * 2 + 0];
    float w1 = cw[o * 1024 + k * 2 + 1];
    wbt[(size_t)o * 1024 + k]      = f2bf(w0 - w1);
    wbt[(size_t)o * 1024 + KH + k] = f2bf(w1);
  }
}

// Fused LN + color-conv + bias + relu + residual.
// Block: 16 positions (96 j-rows) x 512 o-cols. 1024 threads = 16 waves (2x8).
// K-loop: K'=1024 (k<512: xn, k>=512: xsum), BK=64, 16 steps, 2 barriers/step.
__global__ __launch_bounds__(1024) void fused_main(
    const float* __restrict__ x,
    const unsigned short* __restrict__ wbt,
    const float* __restrict__ bias,
    const float* __restrict__ gamma,
    const float* __restrict__ betan,
    float* __restrict__ out)
{
  __shared__ unsigned short As[96 * 64];    // 12 KB, swizzled rows of 128B
  __shared__ unsigned short Bs[512 * 64];   // 64 KB, swizzled rows of 128B
  __shared__ unsigned short sxb[16 * 512];  // 16 KB, normalized xsum (bf16)
  __shared__ float gb[1024];                // gamma[0..512) | beta[0..512)
  __shared__ float st[32];                  // (mean, rstd) per local position

  const int tid  = threadIdx.x;
  const int lane = tid & 63;
  const int wid  = tid >> 6;     // 0..15
  const int wm   = wid >> 3;     // 0..1  -> 48-row half
  const int wn   = wid & 7;      // 0..7  -> 64-col slice
  const int r0   = blockIdx.x * 16;

  if (tid < 512) gb[tid] = gamma[tid];
  else           gb[tid] = betan[tid - 512];
  __syncthreads();

  // ---- prologue: wave `wid` owns position r0+wid; LN stats + normalized xsum ----
  {
    const float* xr = x + (size_t)(r0 + wid) * DF;
    const f32x4* x4 = (const f32x4*)(xr + lane * 48);   // 8 complete k-groups/lane
    f32x4 q[12];
    #pragma unroll
    for (int i = 0; i < 12; i++) q[i] = x4[i];
    float vv[48];
    #pragma unroll
    for (int i = 0; i < 12; i++) {
      vv[i*4+0] = q[i].x; vv[i*4+1] = q[i].y; vv[i*4+2] = q[i].z; vv[i*4+3] = q[i].w;
    }
    float s = 0.f, sq = 0.f;
    #pragma unroll
    for (int i = 0; i < 48; i++) { s += vv[i]; sq += vv[i] * vv[i]; }
    #pragma unroll
    for (int off = 32; off >= 1; off >>= 1) {
      s  += __shfl_xor(s,  off);
      sq += __shfl_xor(sq, off);
    }
    float mean = s * (1.f / 3072.f);
    float var  = sq * (1.f / 3072.f) - mean * mean;
    float rstd = rsqrtf(var + EPSF);
    if (lane == 0) { st[wid * 2] = mean; st[wid * 2 + 1] = rstd; }
    bf16x8 sv;
    #pragma unroll
    for (int g = 0; g < 8; g++) {
      float sraw = 0.f;
      #pragma unroll
      for (int e = 0; e < 6; e++) sraw += vv[g * 6 + e];
      int k = lane * 8 + g;
      float val = (sraw - 6.f * mean) * rstd * gb[k] + 6.f * gb[KH + k];
      sv[g] = (short)f2bf(val);
    }
    *(bf16x8*)((char*)sxb + wid * 1024 + lane * 16) = sv;
  }

  f32x4 acc[3][4];
  #pragma unroll
  for (int m = 0; m < 3; m++) {
    #pragma unroll
    for (int n = 0; n < 4; n++) acc[m][n] = (f32x4){0.f, 0.f, 0.f, 0.f};
  }

  const int jA  = tid >> 3;      // row 0..95 for tid<768
  const int chA = tid & 7;       // 16B chunk 0..7
  const int rlA = jA / 6;
  const int dA  = jA - rlA * 6;

  __syncthreads();               // st + sxb ready

  for (int s = 0; s < 16; s++) {
    // ---- stage A (xn) for k' < 512 ----
    if (s < 8 && tid < 768) {
      const float mean = st[rlA * 2], rstd = st[rlA * 2 + 1];
      const float* xp = x + (size_t)(r0 + rlA) * DF + dA;
      const int kb = s * 64 + chA * 8;
      bf16x8 av;
      #pragma unroll
      for (int i = 0; i < 8; i++) {
        int k = kb + i;
        float xn = (xp[(size_t)k * 6] - mean) * rstd * gb[k] + gb[KH + k];
        av[i] = (short)f2bf(xn);
      }
      *(bf16x8*)((char*)As + jA * 128 + ((chA * 16) ^ ((jA & 7) << 4))) = av;
    }
    // ---- stage B (weights, L2-resident) ----
    {
      const int kcol = s * 64;
      #pragma unroll
      for (int ii = 0; ii < 4; ii++) {
        int cid  = tid + ii * 1024;
        int orow = cid >> 3;
        int oc   = cid & 7;
        bf16x8 wv = *(const bf16x8*)(wbt + (size_t)orow * 1024 + kcol + oc * 8);
        *(bf16x8*)((char*)Bs + orow * 128 + ((oc * 16) ^ ((orow & 7) << 4))) = wv;
      }
    }
    __syncthreads();
    // ---- MFMA ----
    #pragma unroll
    for (int kk = 0; kk < 2; kk++) {
      bf16x8 af[3], bfv[4];
      if (s < 8) {
        #pragma unroll
        for (int m = 0; m < 3; m++) {
          int row = wm * 48 + m * 16 + (lane & 15);
          int col = (kk * 64 + ((lane >> 4) << 4)) ^ ((row & 7) << 4);
          af[m] = *(const bf16x8*)((const char*)As + row * 128 + col);
        }
      } else {
        #pragma unroll
        for (int m = 0; m < 3; m++) {
          int row = wm * 48 + m * 16 + (lane & 15);
          int rl  = row / 6;
          int kbyte = (s - 8) * 128 + kk * 64 + ((lane >> 4) << 4);
          af[m] = *(const bf16x8*)((const char*)sxb + rl * 1024 + kbyte);
        }
      }
      #pragma unroll
      for (int n = 0; n < 4; n++) {
        int row = wn * 64 + n * 16 + (lane & 15);
        int col = (kk * 64 + ((lane >> 4) << 4)) ^ ((row & 7) << 4);
        bfv[n] = *(const bf16x8*)((const char*)Bs + row * 128 + col);
      }
      #pragma unroll
      for (int m = 0; m < 3; m++) {
        #pragma unroll
        for (int n = 0; n < 4; n++) {
          acc[m][n] = __builtin_amdgcn_mfma_f32_16x16x32_bf16(af[m], bfv[n], acc[m][n], 0, 0, 0);
        }
      }
    }
    __syncthreads();
  }

  // ---- epilogue: out = x + relu(acc + bias) ----
  const int rv = ((lane >> 4) << 2);
  const int co = lane & 15;
  #pragma unroll
  for (int n = 0; n < 4; n++) {
    const int o = wn * 64 + n * 16 + co;
    const float bv = bias[o];
    #pragma unroll
    for (int m = 0; m < 3; m++) {
      #pragma unroll
      for (int v = 0; v < 4; v++) {
        int jj = wm * 48 + m * 16 + rv + v;
        int rr = jj / 6;
        int dd = jj - rr * 6;
        size_t addr = (size_t)(r0 + rr) * DF + o * 6 + dd;
        float h = acc[m][n][v] + bv;
        h = fmaxf(h, 0.f);
        out[addr] = x[addr] + h;
      }
    }
  }
}

extern "C" void kernel_launch(void* const* d_in, const int* in_sizes, int n_in,
                              void* d_out, int out_size, void* d_ws, size_t ws_size,
                              hipStream_t stream) {
  (void)n_in; (void)out_size; (void)ws_size;
  const float* x  = (const float*)d_in[0];
  const float* cw = (const float*)d_in[1];
  const float* cb = (const float*)d_in[2];
  const float* nw = (const float*)d_in[3];
  const float* nb = (const float*)d_in[4];
  float* out = (float*)d_out;
  unsigned short* wbt = (unsigned short*)d_ws;   // 1 MB packed bf16 weights

  prep_w<<<512, 256, 0, stream>>>(cw, wbt);

  const int R = in_sizes[0] / DF;                // 24576 positions
  fused_main<<<R / 16, 1024, 0, stream>>>(x, wbt, cb, nw, nb, out);
}